// Round 1
// baseline (1292.693 us; speedup 1.0000x reference)
//
#include <hip/hip_runtime.h>
#include <math.h>

#define C 64           // feature width for all layers
#define NEG_SLOPE 0.2f

// ---- ordered-uint encoding for float atomicMax (handles negatives) ----
__device__ __forceinline__ unsigned encf(float f) {
    unsigned u = __float_as_uint(f);
    return (u & 0x80000000u) ? ~u : (u | 0x80000000u);
}
__device__ __forceinline__ float decf(unsigned u) {
    return (u & 0x80000000u) ? __uint_as_float(u & 0x7FFFFFFFu)
                             : __uint_as_float(~u);
}
#define ENC_NEG_INF 0x007FFFFFu   // encf(-inf)

// ---- K0: wv[k] = sum_c W[k][c] * att[c]  (folds W_dst @ att_dst) ----
__global__ void k_wvec(const float* __restrict__ W, const float* __restrict__ att,
                       float* __restrict__ wv) {
    int k = threadIdx.x;  // 64 threads
    float s = 0.f;
    #pragma unroll
    for (int c = 0; c < C; ++c) s = fmaf(W[k * C + c], att[c], s);
    wv[k] = s;
}

// ---- K1: per node n (one wave per node):
//   xs[n][c] = (x @ W_src)[n][c]
//   out[n][c] = (x @ W_lin)[n][c] + b_conv[c] + b_lin[c]   (accumulator init)
//   a_s[n] = xs[n] . att_src ;  a_d[n] = x[n] . wd
//   mEnc[n] = enc(-inf) ; denom[n] = 0
#define NODES_PER_BLOCK 32
__global__ __launch_bounds__(256) void k_transform(
    const float* __restrict__ x,
    const float* __restrict__ Wsrc,
    const float* __restrict__ Wlin,
    const float* __restrict__ att_src,
    const float* __restrict__ wd,
    const float* __restrict__ b_conv,
    const float* __restrict__ b_lin,
    float* __restrict__ xs,
    float* __restrict__ a_s,
    float* __restrict__ a_d,
    float* __restrict__ outbuf,
    unsigned* __restrict__ mEnc,
    float* __restrict__ denom,
    int nNodes)
{
    __shared__ float sWs[C * C];
    __shared__ float sWl[C * C];
    for (int i = threadIdx.x; i < C * C; i += blockDim.x) {
        sWs[i] = Wsrc[i];
        sWl[i] = Wlin[i];
    }
    __syncthreads();

    const int lane = threadIdx.x & 63;
    const int grp  = threadIdx.x >> 6;     // wave id in block (0..3)
    const float attv = att_src[lane];
    const float wdv  = wd[lane];
    const float bias = b_conv[lane] + b_lin[lane];
    const int base = blockIdx.x * NODES_PER_BLOCK;

    for (int it = 0; it < NODES_PER_BLOCK / 4; ++it) {
        int n = base + it * 4 + grp;
        if (n >= nNodes) continue;
        float xv = x[(size_t)n * C + lane];
        float accS = 0.f, accL = 0.f;
        #pragma unroll
        for (int k = 0; k < C; ++k) {
            float xk = __shfl(xv, k);
            accS = fmaf(xk, sWs[k * C + lane], accS);
            accL = fmaf(xk, sWl[k * C + lane], accL);
        }
        xs[(size_t)n * C + lane]     = accS;
        outbuf[(size_t)n * C + lane] = accL + bias;

        float rs = accS * attv;
        float rd = xv * wdv;
        #pragma unroll
        for (int m = 32; m > 0; m >>= 1) {
            rs += __shfl_xor(rs, m);
            rd += __shfl_xor(rd, m);
        }
        if (lane == 0) {
            a_s[n] = rs;
            a_d[n] = rd;
            mEnc[n] = ENC_NEG_INF;
            denom[n] = 0.f;
        }
    }
}

// ---- K2: e = leaky_relu(a_s[src] + a_d[dst]); segment max over dst ----
__global__ __launch_bounds__(256) void k_edge_max(
    const int* __restrict__ src, const int* __restrict__ dst,
    const float* __restrict__ a_s, const float* __restrict__ a_d,
    float* __restrict__ ebuf, unsigned* __restrict__ mEnc, int nE)
{
    for (int e = blockIdx.x * blockDim.x + threadIdx.x; e < nE;
         e += gridDim.x * blockDim.x) {
        int s = src[e], d = dst[e];
        float v = a_s[s] + a_d[d];
        v = v > 0.f ? v : NEG_SLOPE * v;
        ebuf[e] = v;
        atomicMax(&mEnc[d], encf(v));
    }
}

// ---- K3: ex = exp(e - m[dst]); segment sum over dst ----
__global__ __launch_bounds__(256) void k_edge_exp(
    const int* __restrict__ dst,
    float* __restrict__ ebuf,
    const unsigned* __restrict__ mEnc,
    float* __restrict__ denom, int nE)
{
    for (int e = blockIdx.x * blockDim.x + threadIdx.x; e < nE;
         e += gridDim.x * blockDim.x) {
        int d = dst[e];
        float m = decf(mEnc[d]);
        float ex = __expf(ebuf[e] - m);
        ebuf[e] = ex;
        unsafeAtomicAdd(&denom[d], ex);
    }
}

// ---- K4: out[dst] += xs[src] * (ex / denom[dst]); wave(64 lanes)=64 chans ----
__global__ __launch_bounds__(256) void k_edge_msg(
    const int* __restrict__ src, const int* __restrict__ dst,
    const float* __restrict__ ebuf, const float* __restrict__ denom,
    const float* __restrict__ xs, float* __restrict__ outbuf, int nE)
{
    const int lane = threadIdx.x & 63;
    const int grp  = threadIdx.x >> 6;
    const int groupsPerGrid = gridDim.x * (blockDim.x >> 6);
    for (int e = blockIdx.x * (blockDim.x >> 6) + grp; e < nE; e += groupsPerGrid) {
        int s = src[e], d = dst[e];
        float alpha = ebuf[e] / denom[d];
        float v = xs[(size_t)s * C + lane] * alpha;
        unsafeAtomicAdd(&outbuf[(size_t)d * C + lane], v);
    }
}

// ---- K5: row L2-normalize, in place ----
__global__ __launch_bounds__(256) void k_normalize(float* __restrict__ out, int nNodes)
{
    const int lane = threadIdx.x & 63;
    const int grp  = threadIdx.x >> 6;
    const int groups = gridDim.x * (blockDim.x >> 6);
    for (int n = blockIdx.x * (blockDim.x >> 6) + grp; n < nNodes; n += groups) {
        float v = out[(size_t)n * C + lane];
        float ss = v * v;
        #pragma unroll
        for (int m = 32; m > 0; m >>= 1) ss += __shfl_xor(ss, m);
        float nrm = fmaxf(sqrtf(ss), 1e-12f);
        out[(size_t)n * C + lane] = v / nrm;
    }
}

extern "C" void kernel_launch(void* const* d_in, const int* in_sizes, int n_in,
                              void* d_out, int out_size, void* d_ws, size_t ws_size,
                              hipStream_t stream) {
    const float* x  = (const float*)d_in[0];
    const int*   ei = (const int*)d_in[1];
    const int N = in_sizes[0] / C;
    const int E = in_sizes[1] / 2;
    const int* srcIdx = ei;
    const int* dstIdx = ei + E;

    // workspace layout
    float* w = (float*)d_ws;
    float* xs   = w;  w += (size_t)N * C;
    float* hbuf = w;  w += (size_t)N * C;
    float* ebuf = w;  w += (size_t)E;
    unsigned* mEnc = (unsigned*)w; w += N;
    float* den  = w;  w += N;
    float* a_s  = w;  w += N;
    float* a_d  = w;  w += N;
    float* wvec = w;  w += C;

    const float* Wsrc1 = (const float*)d_in[2];
    const float* Wdst1 = (const float*)d_in[3];
    const float* atts1 = (const float*)d_in[4];
    const float* attd1 = (const float*)d_in[5];
    const float* bcv1  = (const float*)d_in[6];
    const float* Wlin1 = (const float*)d_in[7];
    const float* blin1 = (const float*)d_in[8];
    const float* Wsrc2 = (const float*)d_in[9];
    const float* Wdst2 = (const float*)d_in[10];
    const float* atts2 = (const float*)d_in[11];
    const float* attd2 = (const float*)d_in[12];
    const float* bcv2  = (const float*)d_in[13];
    const float* Wlin2 = (const float*)d_in[14];
    const float* blin2 = (const float*)d_in[15];

    float* out = (float*)d_out;
    const int tblocks = (N + NODES_PER_BLOCK - 1) / NODES_PER_BLOCK;

    // ---------------- layer 1: x -> hbuf ----------------
    k_wvec<<<1, 64, 0, stream>>>(Wdst1, attd1, wvec);
    k_transform<<<tblocks, 256, 0, stream>>>(x, Wsrc1, Wlin1, atts1, wvec,
                                             bcv1, blin1, xs, a_s, a_d,
                                             hbuf, mEnc, den, N);
    k_edge_max<<<2048, 256, 0, stream>>>(srcIdx, dstIdx, a_s, a_d, ebuf, mEnc, E);
    k_edge_exp<<<2048, 256, 0, stream>>>(dstIdx, ebuf, mEnc, den, E);
    k_edge_msg<<<4096, 256, 0, stream>>>(srcIdx, dstIdx, ebuf, den, xs, hbuf, E);

    // ---------------- layer 2: hbuf -> out ----------------
    k_wvec<<<1, 64, 0, stream>>>(Wdst2, attd2, wvec);
    k_transform<<<tblocks, 256, 0, stream>>>(hbuf, Wsrc2, Wlin2, atts2, wvec,
                                             bcv2, blin2, xs, a_s, a_d,
                                             out, mEnc, den, N);
    k_edge_max<<<2048, 256, 0, stream>>>(srcIdx, dstIdx, a_s, a_d, ebuf, mEnc, E);
    k_edge_exp<<<2048, 256, 0, stream>>>(dstIdx, ebuf, mEnc, den, E);
    k_edge_msg<<<4096, 256, 0, stream>>>(srcIdx, dstIdx, ebuf, den, xs, out, E);

    // ---------------- final normalize ----------------
    k_normalize<<<1024, 256, 0, stream>>>(out, N);
}

// Round 2
// 663.598 us; speedup vs baseline: 1.9480x; 1.9480x over previous
//
#include <hip/hip_runtime.h>
#include <math.h>

#define C 64           // feature width for all layers
#define NEG_SLOPE 0.2f

// ---- K0: wv[k] = sum_c W[k][c] * att[c]  (folds W_dst @ att_dst) ----
__global__ void k_wvec(const float* __restrict__ W, const float* __restrict__ att,
                       float* __restrict__ wv) {
    int k = threadIdx.x;  // 64 threads
    float s = 0.f;
    #pragma unroll
    for (int c = 0; c < C; ++c) s = fmaf(W[k * C + c], att[c], s);
    wv[k] = s;
}

// ---- K1: per node n (one wave per node):
//   xs[n][c] = (x @ W_src)[n][c]
//   out[n][c] = (x @ W_lin)[n][c] + b_conv[c] + b_lin[c]   (accumulator init)
//   a_s[n] = xs[n] . att_src ;  a_d[n] = x[n] . wd
#define NODES_PER_BLOCK 32
__global__ __launch_bounds__(256) void k_transform(
    const float* __restrict__ x,
    const float* __restrict__ Wsrc,
    const float* __restrict__ Wlin,
    const float* __restrict__ att_src,
    const float* __restrict__ wd,
    const float* __restrict__ b_conv,
    const float* __restrict__ b_lin,
    float* __restrict__ xs,
    float* __restrict__ a_s,
    float* __restrict__ a_d,
    float* __restrict__ outbuf,
    int nNodes)
{
    __shared__ float sWs[C * C];
    __shared__ float sWl[C * C];
    for (int i = threadIdx.x; i < C * C; i += blockDim.x) {
        sWs[i] = Wsrc[i];
        sWl[i] = Wlin[i];
    }
    __syncthreads();

    const int lane = threadIdx.x & 63;
    const int grp  = threadIdx.x >> 6;     // wave id in block (0..3)
    const float attv = att_src[lane];
    const float wdv  = wd[lane];
    const float bias = b_conv[lane] + b_lin[lane];
    const int base = blockIdx.x * NODES_PER_BLOCK;

    for (int it = 0; it < NODES_PER_BLOCK / 4; ++it) {
        int n = base + it * 4 + grp;
        if (n >= nNodes) continue;
        float xv = x[(size_t)n * C + lane];
        float accS = 0.f, accL = 0.f;
        #pragma unroll
        for (int k = 0; k < C; ++k) {
            float xk = __shfl(xv, k);
            accS = fmaf(xk, sWs[k * C + lane], accS);
            accL = fmaf(xk, sWl[k * C + lane], accL);
        }
        xs[(size_t)n * C + lane]     = accS;
        outbuf[(size_t)n * C + lane] = accL + bias;

        float rs = accS * attv;
        float rd = xv * wdv;
        #pragma unroll
        for (int m = 32; m > 0; m >>= 1) {
            rs += __shfl_xor(rs, m);
            rd += __shfl_xor(rd, m);
        }
        if (lane == 0) {
            a_s[n] = rs;
            a_d[n] = rd;
        }
    }
}

// ============================ CSR build ============================

__global__ __launch_bounds__(256) void k_zero(int* __restrict__ p, int n) {
    for (int i = blockIdx.x * blockDim.x + threadIdx.x; i < n;
         i += gridDim.x * blockDim.x) p[i] = 0;
}

__global__ __launch_bounds__(256) void k_hist(const int* __restrict__ dst,
                                              int* __restrict__ cnt, int nE) {
    for (int e = blockIdx.x * blockDim.x + threadIdx.x; e < nE;
         e += gridDim.x * blockDim.x) atomicAdd(&cnt[dst[e]], 1);
}

// block-level scan: 256 threads x 4 elems = 1024 per block
__global__ __launch_bounds__(256) void k_scan_block(
    const int* __restrict__ cnt, int* __restrict__ rowptr,
    int* __restrict__ partials, int n)
{
    __shared__ int sdata[256];
    const int base = blockIdx.x * 1024;
    const int t = threadIdx.x;
    int v[4]; int s = 0;
    #pragma unroll
    for (int i = 0; i < 4; ++i) {
        int idx = base + t * 4 + i;
        v[i] = (idx < n) ? cnt[idx] : 0;
        s += v[i];
    }
    sdata[t] = s;
    __syncthreads();
    for (int off = 1; off < 256; off <<= 1) {
        int x = (t >= off) ? sdata[t - off] : 0;
        __syncthreads();
        sdata[t] += x;
        __syncthreads();
    }
    int run = sdata[t] - s;   // exclusive prefix of this thread
    #pragma unroll
    for (int i = 0; i < 4; ++i) {
        int idx = base + t * 4 + i;
        if (idx < n) rowptr[idx] = run;
        run += v[i];
    }
    if (t == 255) partials[blockIdx.x] = sdata[255];
}

// single-block exclusive scan of <=256 partials
__global__ __launch_bounds__(256) void k_scan_partials(int* __restrict__ partials, int nb) {
    __shared__ int sd[256];
    const int t = threadIdx.x;
    int v = (t < nb) ? partials[t] : 0;
    sd[t] = v;
    __syncthreads();
    for (int off = 1; off < 256; off <<= 1) {
        int x = (t >= off) ? sd[t - off] : 0;
        __syncthreads();
        sd[t] += x;
        __syncthreads();
    }
    if (t < nb) partials[t] = sd[t] - v;   // exclusive
}

__global__ __launch_bounds__(256) void k_scan_add(
    int* __restrict__ rowptr, int* __restrict__ cursor,
    const int* __restrict__ partials, int n, int nE)
{
    for (int i = blockIdx.x * blockDim.x + threadIdx.x; i < n;
         i += gridDim.x * blockDim.x) {
        int r = rowptr[i] + partials[i >> 10];
        rowptr[i] = r;
        cursor[i] = r;
    }
    if (blockIdx.x == 0 && threadIdx.x == 0) rowptr[n] = nE;
}

__global__ __launch_bounds__(256) void k_scatter(
    const int* __restrict__ src, const int* __restrict__ dst,
    int* __restrict__ cursor, int* __restrict__ csr_src, int nE)
{
    for (int e = blockIdx.x * blockDim.x + threadIdx.x; e < nE;
         e += gridDim.x * blockDim.x) {
        int pos = atomicAdd(&cursor[dst[e]], 1);
        csr_src[pos] = src[e];
    }
}

// ============== fused per-dst-node GAT aggregation ==============
// One wave per dst node. Pass 1: segment max (lane-strided).
// Pass 2+3 fused: per 64-edge chunk each lane computes ex; shuffle-broadcast
// (ex, src) and accumulate acc[c] += ex * xs[src][c]; divide by sum at end.
__global__ __launch_bounds__(256) void k_gat_node(
    const int* __restrict__ rowptr, const int* __restrict__ csr_src,
    const float* __restrict__ a_s, const float* __restrict__ a_d,
    const float* __restrict__ xs, float* __restrict__ outbuf, int nNodes)
{
    const int lane = threadIdx.x & 63;
    const int n = (blockIdx.x * blockDim.x + threadIdx.x) >> 6;
    if (n >= nNodes) return;
    const int start = rowptr[n], end = rowptr[n + 1];
    if (start == end) return;            // keep the linear-skip part only
    const float a_dn = a_d[n];

    // pass 1: segment max
    float mloc = -INFINITY;
    for (int j = start + lane; j < end; j += 64) {
        float ev = a_s[csr_src[j]] + a_dn;
        ev = ev > 0.f ? ev : NEG_SLOPE * ev;
        mloc = fmaxf(mloc, ev);
    }
    #pragma unroll
    for (int m = 32; m > 0; m >>= 1) mloc = fmaxf(mloc, __shfl_xor(mloc, m));

    // pass 2+3
    float acc = 0.f;
    float sloc = 0.f;
    for (int jb = start; jb < end; jb += 64) {
        const int cnt = min(64, end - jb);
        float ex = 0.f; int sidx = 0;
        if (lane < cnt) {
            sidx = csr_src[jb + lane];
            float ev = a_s[sidx] + a_dn;
            ev = ev > 0.f ? ev : NEG_SLOPE * ev;
            ex = __expf(ev - mloc);
            sloc += ex;
        }
        int t = 0;
        for (; t + 1 < cnt; t += 2) {
            float w0 = __shfl(ex, t);     int s0 = __shfl(sidx, t);
            float w1 = __shfl(ex, t + 1); int s1 = __shfl(sidx, t + 1);
            float v0 = xs[(size_t)s0 * C + lane];
            float v1 = xs[(size_t)s1 * C + lane];
            acc = fmaf(w0, v0, acc);
            acc = fmaf(w1, v1, acc);
        }
        if (t < cnt) {
            float w0 = __shfl(ex, t); int s0 = __shfl(sidx, t);
            acc = fmaf(w0, xs[(size_t)s0 * C + lane], acc);
        }
    }
    #pragma unroll
    for (int m = 32; m > 0; m >>= 1) sloc += __shfl_xor(sloc, m);

    outbuf[(size_t)n * C + lane] += acc / sloc;
}

// ---- K5: row L2-normalize, in place ----
__global__ __launch_bounds__(256) void k_normalize(float* __restrict__ out, int nNodes)
{
    const int lane = threadIdx.x & 63;
    const int grp  = threadIdx.x >> 6;
    const int groups = gridDim.x * (blockDim.x >> 6);
    for (int n = blockIdx.x * (blockDim.x >> 6) + grp; n < nNodes; n += groups) {
        float v = out[(size_t)n * C + lane];
        float ss = v * v;
        #pragma unroll
        for (int m = 32; m > 0; m >>= 1) ss += __shfl_xor(ss, m);
        float nrm = fmaxf(sqrtf(ss), 1e-12f);
        out[(size_t)n * C + lane] = v / nrm;
    }
}

extern "C" void kernel_launch(void* const* d_in, const int* in_sizes, int n_in,
                              void* d_out, int out_size, void* d_ws, size_t ws_size,
                              hipStream_t stream) {
    const float* x  = (const float*)d_in[0];
    const int*   ei = (const int*)d_in[1];
    const int N = in_sizes[0] / C;
    const int E = in_sizes[1] / 2;
    const int* srcIdx = ei;
    const int* dstIdx = ei + E;

    // workspace layout
    char* w = (char*)d_ws;
    float* xs      = (float*)w; w += (size_t)N * C * 4;
    float* hbuf    = (float*)w; w += (size_t)N * C * 4;
    float* a_s     = (float*)w; w += (size_t)N * 4;
    float* a_d     = (float*)w; w += (size_t)N * 4;
    float* wvec    = (float*)w; w += C * 4;
    int*   dcount  = (int*)w;   w += (size_t)N * 4;
    int*   rowptr  = (int*)w;   w += ((size_t)N + 1) * 4;
    int*   cursor  = (int*)w;   w += (size_t)N * 4;
    int*   partials= (int*)w;   w += 256 * 4;
    int*   csr_src = (int*)w;   w += (size_t)E * 4;

    const float* Wsrc1 = (const float*)d_in[2];
    const float* Wdst1 = (const float*)d_in[3];
    const float* atts1 = (const float*)d_in[4];
    const float* attd1 = (const float*)d_in[5];
    const float* bcv1  = (const float*)d_in[6];
    const float* Wlin1 = (const float*)d_in[7];
    const float* blin1 = (const float*)d_in[8];
    const float* Wsrc2 = (const float*)d_in[9];
    const float* Wdst2 = (const float*)d_in[10];
    const float* atts2 = (const float*)d_in[11];
    const float* attd2 = (const float*)d_in[12];
    const float* bcv2  = (const float*)d_in[13];
    const float* Wlin2 = (const float*)d_in[14];
    const float* blin2 = (const float*)d_in[15];

    float* out = (float*)d_out;
    const int tblocks = (N + NODES_PER_BLOCK - 1) / NODES_PER_BLOCK;
    const int nodeWaveBlocks = (N + 3) / 4;          // 1 wave per node, 4 waves/block
    const int nb = (N + 1023) / 1024;                // scan blocks (<=256 required)

    // ---------------- CSR build (per-call, deterministic) ----------------
    k_zero<<<512, 256, 0, stream>>>(dcount, N);
    k_hist<<<2048, 256, 0, stream>>>(dstIdx, dcount, E);
    k_scan_block<<<nb, 256, 0, stream>>>(dcount, rowptr, partials, N);
    k_scan_partials<<<1, 256, 0, stream>>>(partials, nb);
    k_scan_add<<<512, 256, 0, stream>>>(rowptr, cursor, partials, N, E);
    k_scatter<<<2048, 256, 0, stream>>>(srcIdx, dstIdx, cursor, csr_src, E);

    // ---------------- layer 1: x -> hbuf ----------------
    k_wvec<<<1, 64, 0, stream>>>(Wdst1, attd1, wvec);
    k_transform<<<tblocks, 256, 0, stream>>>(x, Wsrc1, Wlin1, atts1, wvec,
                                             bcv1, blin1, xs, a_s, a_d,
                                             hbuf, N);
    k_gat_node<<<nodeWaveBlocks, 256, 0, stream>>>(rowptr, csr_src, a_s, a_d,
                                                   xs, hbuf, N);

    // ---------------- layer 2: hbuf -> out ----------------
    k_wvec<<<1, 64, 0, stream>>>(Wdst2, attd2, wvec);
    k_transform<<<tblocks, 256, 0, stream>>>(hbuf, Wsrc2, Wlin2, atts2, wvec,
                                             bcv2, blin2, xs, a_s, a_d,
                                             out, N);
    k_gat_node<<<nodeWaveBlocks, 256, 0, stream>>>(rowptr, csr_src, a_s, a_d,
                                                   xs, out, N);

    // ---------------- final normalize ----------------
    k_normalize<<<1024, 256, 0, stream>>>(out, N);
}